// Round 7
// baseline (73.945 us; speedup 1.0000x reference)
//
#include <hip/hip_runtime.h>
#include <math.h>

typedef __bf16 bf16x8 __attribute__((ext_vector_type(8)));
typedef float f32x4 __attribute__((ext_vector_type(4)));
typedef unsigned short u16t;

namespace {
constexpr int B_ = 32, CIN = 16, CSP = 15, L_ = 16384;
constexpr int KS = 9, PAD = 4, OUTC = 64, NW = 63, CD = 136;
constexpr int KT = 160;        // padded K: 10 taps * 16 channel slots
constexpr int NKS = 5;         // MFMA K-steps of 32
constexpr int BP = 512;        // positions per block (main)
constexpr int CH = 128;        // positions per reduce chunk

// d_ws layout
constexpr int XTROWS = 16400;                                    // 4 lead + 16384 + 12 tail
constexpr size_t WS_WBF = 0;                                     // [64][160] bf16 = 20480 B
constexpr size_t WS_XT = 20480;                                  // [32][16400][16] bf16
constexpr size_t WS_CSQ = WS_XT + (size_t)B_ * XTROWS * 16 * 2;  // [32][16400] f32
constexpr size_t WS_TOTAL = WS_CSQ + (size_t)B_ * XTROWS * 4;    // 18,913,280 B

__device__ inline u16t f2bf(float v) {
  unsigned ui = __float_as_uint(v);
  return (u16t)((ui + 0x7fffu + ((ui >> 16) & 1u)) >> 16);
}
__device__ inline float bf2f(u16t u) { return __uint_as_float(((unsigned)u) << 16); }
}

// ---- prep 1: W (63x136 f32) -> wbf[64][160] bf16, k = jt*16 + cs; pads zeroed.
__global__ void prep_w(const float* __restrict__ W, u16t* __restrict__ wbf) {
  int i = blockIdx.x * 256 + threadIdx.x;
  if (i >= OUTC * KT) return;
  int o = i / KT, kk = i - o * KT;
  int jt = kk >> 4, cs = kk & 15;
  float v = 0.f;
  if (o < NW && jt < KS && cs < CSP) v = W[o * CD + 1 + jt * CSP + cs];
  wbf[i] = f2bf(v);
}

// ---- prep 2: transpose x -> xT[b][4+pos][16] bf16 (ch15=0, edge rows zero)
//              and csq[b][4+pos] = sum_c x^2 (edge zero).
__global__ void prep_x2(const float* __restrict__ x, u16t* __restrict__ xT,
                        float* __restrict__ csq) {
  const int tid = threadIdx.x;
  const int b = blockIdx.y;
  const int p = blockIdx.x * 256 + tid;
  float s = 0.f;
  union { u16t h[16]; uint4 u[2]; } pk;
  const float* xb = x + (size_t)b * CIN * L_;
#pragma unroll
  for (int c = 0; c < CSP; ++c) {
    float v = xb[(size_t)(c + 1) * L_ + p];
    s = fmaf(v, v, s);
    pk.h[c] = f2bf(v);
  }
  pk.h[15] = 0;
  uint4* dst = (uint4*)(xT + ((size_t)b * XTROWS + p + 4) * 16);
  dst[0] = pk.u[0];
  dst[1] = pk.u[1];
  csq[(size_t)b * XTROWS + p + 4] = s;
  // zero pads (lead rows 0..3, tail rows 16388..16399)
  if (blockIdx.x == 0 && tid < 4) {
    uint4* z = (uint4*)(xT + ((size_t)b * XTROWS + tid) * 16);
    z[0] = make_uint4(0, 0, 0, 0);
    z[1] = make_uint4(0, 0, 0, 0);
    csq[(size_t)b * XTROWS + tid] = 0.f;
  }
  if (blockIdx.x == (L_ / 256 - 1) && tid < 12) {
    uint4* z = (uint4*)(xT + ((size_t)b * XTROWS + L_ + 4 + tid) * 16);
    z[0] = make_uint4(0, 0, 0, 0);
    z[1] = make_uint4(0, 0, 0, 0);
    csq[(size_t)b * XTROWS + L_ + 4 + tid] = 0.f;
  }
}

// ---- main: MFMA from global xT; LDS only for the h^2 channel-reduce.
__global__ __launch_bounds__(256, 4)
void lorentz_main(const u16t* __restrict__ xT, const float* __restrict__ csq,
                  const float* __restrict__ W, const float* __restrict__ bias,
                  const u16t* __restrict__ wbf, float* __restrict__ out) {
  __shared__ float red[CH][68];  // [pos][ch] f32, 34816 B

  const int tid = threadIdx.x;
  const int b = blockIdx.y;
  const int p0 = blockIdx.x * BP;
  const int wv = tid >> 6;
  const int lane = tid & 63;
  const int q = lane >> 4, r = lane & 15;
  const int jtq = q >> 1, half = q & 1;
  const int row = 16 * wv + r;   // this lane's output channel (W row)

  // W fragments: 5 uint4 = 20 VGPR, register-resident.
  uint4 wfrag[NKS];
#pragma unroll
  for (int ks = 0; ks < NKS; ++ks)
    wfrag[ks] = *(const uint4*)(wbf + row * KT + ks * 32 + q * 8);
  const float w0v = (row < NW) ? W[row * CD] : 0.f;
  const float bv = (row < NW) ? bias[row] : 0.f;

  const u16t* xb = xT + (size_t)b * XTROWS * 16;
  const float* cb = csq + (size_t)b * XTROWS;

  for (int chunk = 0; chunk < BP / CH; ++chunk) {
#pragma unroll 4
    for (int sl = 0; sl < CH / 16; ++sl) {
      const int s = chunk * (CH / 16) + sl;
      const int pb = p0 + s * 16;

      // A fragments: direct global b128; lane (q,r) = patch[pos=pb+r][k=32ks+8q..+7]
      bf16x8 av[NKS];
#pragma unroll
      for (int ks = 0; ks < NKS; ++ks)
        av[ks] = *(const bf16x8*)(xb + (size_t)(pb + r + 2 * ks + jtq) * 16 + half * 8);

      f32x4 acc = {0.f, 0.f, 0.f, 0.f};
#pragma unroll
      for (int ks = 0; ks < NKS; ++ks) {
        union { uint4 u; bf16x8 v; } w;
        w.u = wfrag[ks];
        acc = __builtin_amdgcn_mfma_f32_16x16x32_bf16(av[ks], w.v, acc, 0, 0, 0);
      }

      // time channel: 3 broadcast float4 loads of csq + running 9-window sums
      const float* c0 = cb + pb + q * 4;   // row idx = pb + q*4 (lead pad already +4)
      f32x4 ca = *(const f32x4*)c0;
      f32x4 cm = *(const f32x4*)(c0 + 4);
      f32x4 cc = *(const f32x4*)(c0 + 8);
      float v[12] = {ca[0], ca[1], ca[2], ca[3], cm[0], cm[1], cm[2], cm[3],
                     cc[0], cc[1], cc[2], cc[3]};
      float ws0 = ((v[0] + v[1]) + (v[2] + v[3])) + ((v[4] + v[5]) + (v[6] + v[7])) + v[8];
      float ws1 = ws0 - v[0] + v[9];
      float ws2 = ws1 - v[1] + v[10];
      float ws3 = ws2 - v[2] + v[11];
      const float wsv[4] = {ws0, ws1, ws2, ws3};

      float h[4];
#pragma unroll
      for (int g = 0; g < 4; ++g) {
        float tmg = sqrtf(1.f + wsv[g]);
        float hh = fmaf(w0v, tmg, acc[g]) + bv;
        hh = fmaxf(hh, 0.f);
        h[g] = hh;
        red[sl * 16 + q * 4 + g][row] = hh * hh;  // conflict-free: 32 banks x 2 lanes
      }
      if (row < NW) {
        *(float4*)(out + ((size_t)b * OUTC + row + 1) * L_ + pb + q * 4) =
            make_float4(h[0], h[1], h[2], h[3]);
      }
    }
    __syncthreads();

    // channel-reduce: thread t sums red[t][0..63] via 16 contiguous b128 reads
    if (tid < CH) {
      f32x4 s4 = {0.f, 0.f, 0.f, 0.f};
#pragma unroll
      for (int r4 = 0; r4 < 16; ++r4) s4 += *(const f32x4*)&red[tid][r4 * 4];
      float S = (s4[0] + s4[1]) + (s4[2] + s4[3]);
      out[(size_t)b * OUTC * L_ + p0 + chunk * CH + tid] = sqrtf(1.f + S);
    }
    __syncthreads();
  }
}

// ================= fallback (R5 kernel, used if ws_size is too small) ==========
namespace fb {
constexpr int PP = 256, TILES = 2, XR = 268, RSTR = 24;
constexpr int OFF_XT = 0;
constexpr int OFF_CSQ = OFF_XT + XR * RSTR * 2;
constexpr int OFF_RED = ((OFF_CSQ + XR * 4 + 15) / 16) * 16;
constexpr int LDS_BYTES = OFF_RED + 4 * PP * 4;
}

__global__ __launch_bounds__(256, 4)
void lorentz_fallback(const float* __restrict__ x, const float* __restrict__ W,
                      const float* __restrict__ bias, const u16t* __restrict__ wbf,
                      float* __restrict__ out) {
  using namespace fb;
  __shared__ __align__(16) char lds[LDS_BYTES];
  const int tid = threadIdx.x;
  const int b = blockIdx.y;
  const int wv = tid >> 6;
  const int lane = tid & 63;
  const int q = lane >> 4, r = lane & 15;
  const int jtq = q >> 1, half = q & 1;
  const int row = 16 * wv + r;

  u16t* Xt = (u16t*)(lds + OFF_XT);
  float* csq = (float*)(lds + OFF_CSQ);
  float* red = (float*)(lds + OFF_RED);

  uint4 wfrag[NKS];
#pragma unroll
  for (int ks = 0; ks < NKS; ++ks)
    wfrag[ks] = *(const uint4*)(wbf + row * KT + ks * 32 + q * 8);
  const float w0v = (row < NW) ? W[row * CD] : 0.f;
  const float bv = (row < NW) ? bias[row] : 0.f;

  for (int tile = 0; tile < TILES; ++tile) {
    const int p0 = (blockIdx.x * TILES + tile) * PP;
    for (int t = tid; t < XR; t += 256) Xt[t * RSTR + 15] = 0;
    for (int e4 = tid; e4 < CSP * (XR / 4); e4 += 256) {
      int cs = e4 / (XR / 4);
      int t4 = e4 - cs * (XR / 4);
      int t = 4 * t4;
      int g0 = p0 - PAD + t;
      const float* src = x + ((size_t)b * CIN + cs + 1) * L_ + g0;
      float v0, v1, v2, v3;
      if (g0 >= 0 && g0 + 3 < L_) {
        float4 v = *(const float4*)src;
        v0 = v.x; v1 = v.y; v2 = v.z; v3 = v.w;
      } else {
        v0 = (g0 >= 0 && g0 < L_) ? src[0] : 0.f;
        v1 = (g0 + 1 >= 0 && g0 + 1 < L_) ? src[1] : 0.f;
        v2 = (g0 + 2 >= 0 && g0 + 2 < L_) ? src[2] : 0.f;
        v3 = (g0 + 3 >= 0 && g0 + 3 < L_) ? src[3] : 0.f;
      }
      u16t* dst = Xt + t * RSTR + cs;
      dst[0] = f2bf(v0);
      dst[RSTR] = f2bf(v1);
      dst[2 * RSTR] = f2bf(v2);
      dst[3 * RSTR] = f2bf(v3);
    }
    __syncthreads();
    for (int t = tid; t < XR; t += 256) {
      const uint4* rw = (const uint4*)(Xt + t * RSTR);
      uint4 a = rw[0], c = rw[1];
      unsigned wds[8] = {a.x, a.y, a.z, a.w, c.x, c.y, c.z, c.w};
      float s = 0.f;
#pragma unroll
      for (int i = 0; i < 8; ++i) {
        float lo = bf2f((u16t)(wds[i] & 0xffffu));
        float hi = bf2f((u16t)(wds[i] >> 16));
        s = fmaf(lo, lo, s);
        s = fmaf(hi, hi, s);
      }
      csq[t] = s;
    }
    __syncthreads();
#pragma unroll 4
    for (int s = 0; s < 16; ++s) {
      bf16x8 av[NKS];
#pragma unroll
      for (int ks = 0; ks < NKS; ++ks) {
        int xrow = s * 16 + r + 2 * ks + jtq;
        av[ks] = *(const bf16x8*)(lds + OFF_XT + xrow * (RSTR * 2) + half * 16);
      }
      f32x4 acc = {0.f, 0.f, 0.f, 0.f};
#pragma unroll
      for (int ks = 0; ks < NKS; ++ks) {
        union { uint4 u; bf16x8 v; } w;
        w.u = wfrag[ks];
        acc = __builtin_amdgcn_mfma_f32_16x16x32_bf16(av[ks], w.v, acc, 0, 0, 0);
      }
      const int base = s * 16 + q * 4;
      const f32x4* c4 = (const f32x4*)(csq + base);
      f32x4 ca = c4[0], cm = c4[1], cc = c4[2];
      float v[12] = {ca[0], ca[1], ca[2], ca[3], cm[0], cm[1], cm[2], cm[3],
                     cc[0], cc[1], cc[2], cc[2]};
      v[11] = cc[3];
      float h[4], psum[4];
#pragma unroll
      for (int g = 0; g < 4; ++g) {
        float ss = 0.f;
#pragma unroll
        for (int j = 0; j < KS; ++j) ss += v[g + j];
        float tmg = sqrtf(1.f + ss);
        float hh = fmaf(w0v, tmg, acc[g]) + bv;
        hh = fmaxf(hh, 0.f);
        h[g] = hh;
        psum[g] = hh * hh;
      }
      if (row < NW) {
        *(float4*)(out + ((size_t)b * OUTC + row + 1) * L_ + p0 + s * 16 + q * 4) =
            make_float4(h[0], h[1], h[2], h[3]);
      }
#pragma unroll
      for (int m = 1; m <= 8; m <<= 1) {
#pragma unroll
        for (int g = 0; g < 4; ++g) psum[g] += __shfl_xor(psum[g], m, 64);
      }
      if (r == 0) {
        *(f32x4*)(red + wv * PP + s * 16 + q * 4) =
            (f32x4){psum[0], psum[1], psum[2], psum[3]};
      }
    }
    __syncthreads();
    if (wv == 0) {
      const f32x4* r4 = (const f32x4*)red;
      f32x4 s0 = r4[lane], s1 = r4[64 + lane], s2 = r4[128 + lane], s3 = r4[192 + lane];
      float4 t;
      t.x = sqrtf(1.f + s0[0] + s1[0] + s2[0] + s3[0]);
      t.y = sqrtf(1.f + s0[1] + s1[1] + s2[1] + s3[1]);
      t.z = sqrtf(1.f + s0[2] + s1[2] + s2[2] + s3[2]);
      t.w = sqrtf(1.f + s0[3] + s1[3] + s2[3] + s3[3]);
      *(float4*)(out + (size_t)b * OUTC * L_ + p0 + 4 * lane) = t;
    }
  }
}

extern "C" void kernel_launch(void* const* d_in, const int* in_sizes, int n_in,
                              void* d_out, int out_size, void* d_ws, size_t ws_size,
                              hipStream_t stream) {
  const float* x = (const float*)d_in[0];
  const float* W = (const float*)d_in[1];
  const float* bias = (const float*)d_in[2];
  float* out = (float*)d_out;
  u16t* wbf = (u16t*)((char*)d_ws + WS_WBF);

  hipLaunchKernelGGL(prep_w, dim3((OUTC * KT + 255) / 256), dim3(256), 0, stream, W, wbf);

  if (ws_size >= WS_TOTAL) {
    u16t* xT = (u16t*)((char*)d_ws + WS_XT);
    float* csq = (float*)((char*)d_ws + WS_CSQ);
    hipLaunchKernelGGL(prep_x2, dim3(L_ / 256, B_), dim3(256), 0, stream, x, xT, csq);
    hipLaunchKernelGGL(lorentz_main, dim3(L_ / BP, B_), dim3(256), 0, stream,
                       xT, csq, W, bias, wbf, out);
  } else {
    hipLaunchKernelGGL(lorentz_fallback, dim3(L_ / (fb::PP * fb::TILES), B_), dim3(256),
                       0, stream, x, W, bias, wbf, out);
  }
}

// Round 8
// 58.236 us; speedup vs baseline: 1.2697x; 1.2697x over previous
//
#include <hip/hip_runtime.h>
#include <math.h>

typedef __bf16 bf16x8 __attribute__((ext_vector_type(8)));
typedef float f32x4 __attribute__((ext_vector_type(4)));
typedef unsigned short u16t;

namespace {
constexpr int B_ = 32, CIN = 16, CSP = 15, L_ = 16384;
constexpr int KS = 9, PAD = 4, OUTC = 64, NW = 63, CD = 136;
constexpr int PP = 256;        // positions per block (one tile; grid 2048 = 8 blocks/CU)
constexpr int KT = 160;        // padded K: 10 taps * 16 channel slots
constexpr int NKS = 5;         // MFMA K-steps of 32
constexpr int XR = 268;        // staged rows: max read row 264, pad to /4
constexpr int RSTR = 24;       // Xt row stride in u16 (48 B: 16B-aligned, ~2-way banks)

constexpr int OFF_XT = 0;                                     // [268][24] u16 = 12864 B
constexpr int OFF_CSQ = OFF_XT + XR * RSTR * 2;               // 12864: [268] f32
constexpr int OFF_RED = ((OFF_CSQ + XR * 4 + 15) / 16) * 16;  // 13936: [4][256] f32
constexpr int LDS_BYTES = OFF_RED + 4 * PP * 4;               // 18032 B -> 8 blocks/CU by LDS
static_assert(LDS_BYTES <= 60 * 1024, "LDS overflow");

__device__ inline u16t f2bf(float v) {
  unsigned ui = __float_as_uint(v);
  return (u16t)((ui + 0x7fffu + ((ui >> 16) & 1u)) >> 16);
}
__device__ inline float bf2f(u16t u) { return __uint_as_float(((unsigned)u) << 16); }
}

// Prepack W (63x136 fp32) -> wbf[64][160] bf16, k = jt*16 + cs; pads zeroed.
__global__ void prep_w(const float* __restrict__ W, u16t* __restrict__ wbf) {
  int i = blockIdx.x * 256 + threadIdx.x;
  if (i >= OUTC * KT) return;
  int o = i / KT, kk = i - o * KT;
  int jt = kk >> 4, cs = kk & 15;
  float v = 0.f;
  if (o < NW && jt < KS && cs < CSP) v = W[o * CD + 1 + jt * CSP + cs];
  wbf[i] = f2bf(v);
}

__global__ __launch_bounds__(256, 6)   // cap VGPR at 85 -> 6 waves/SIMD resident
void lorentz_mfma(const float* __restrict__ x, const float* __restrict__ W,
                  const float* __restrict__ bias, const u16t* __restrict__ wbf,
                  float* __restrict__ out) {
  __shared__ __align__(16) char lds[LDS_BYTES];
  const int tid = threadIdx.x;
  const int b = blockIdx.y;
  const int p0 = blockIdx.x * PP;
  const int wv = tid >> 6;
  const int lane = tid & 63;
  const int q = lane >> 4, r = lane & 15;
  const int jtq = q >> 1, half = q & 1;
  const int row = 16 * wv + r;   // this lane's output channel (W row)

  u16t* Xt = (u16t*)(lds + OFF_XT);
  float* csq = (float*)(lds + OFF_CSQ);
  float* red = (float*)(lds + OFF_RED);

  // W fragments: 5 uint4 = 20 VGPR, register-resident.
  uint4 wfrag[NKS];
#pragma unroll
  for (int ks = 0; ks < NKS; ++ks)
    wfrag[ks] = *(const uint4*)(wbf + row * KT + ks * 32 + q * 8);
  const float w0v = (row < NW) ? W[row * CD] : 0.f;
  const float bv = (row < NW) ? bias[row] : 0.f;

  // ---- P1: stage x (channels 1..15) position-major, float4-vectorized
  for (int t = tid; t < XR; t += 256) Xt[t * RSTR + 15] = 0;  // dummy ch, NaN-safe
  for (int e4 = tid; e4 < CSP * (XR / 4); e4 += 256) {
    int cs = e4 / (XR / 4);
    int t4 = e4 - cs * (XR / 4);
    int t = 4 * t4;
    int g0 = p0 - PAD + t;
    const float* src = x + ((size_t)b * CIN + cs + 1) * L_ + g0;
    float v0, v1, v2, v3;
    if (g0 >= 0 && g0 + 3 < L_) {
      float4 v = *(const float4*)src;   // g0 % 4 == 0 -> 16B aligned
      v0 = v.x; v1 = v.y; v2 = v.z; v3 = v.w;
    } else {
      v0 = (g0 >= 0 && g0 < L_) ? src[0] : 0.f;
      v1 = (g0 + 1 >= 0 && g0 + 1 < L_) ? src[1] : 0.f;
      v2 = (g0 + 2 >= 0 && g0 + 2 < L_) ? src[2] : 0.f;
      v3 = (g0 + 3 >= 0 && g0 + 3 < L_) ? src[3] : 0.f;
    }
    u16t* dst = Xt + t * RSTR + cs;
    dst[0] = f2bf(v0);
    dst[RSTR] = f2bf(v1);
    dst[2 * RSTR] = f2bf(v2);
    dst[3 * RSTR] = f2bf(v3);
  }
  __syncthreads();

  // ---- P2: per-window-column sum of squares (ch15 zero, include freely)
  for (int t = tid; t < XR; t += 256) {
    const uint4* rw = (const uint4*)(Xt + t * RSTR);
    uint4 a = rw[0], c = rw[1];
    unsigned wds[8] = {a.x, a.y, a.z, a.w, c.x, c.y, c.z, c.w};
    float s = 0.f;
#pragma unroll
    for (int i = 0; i < 8; ++i) {
      float lo = bf2f((u16t)(wds[i] & 0xffffu));
      float hi = bf2f((u16t)(wds[i] >> 16));
      s = fmaf(lo, lo, s);
      s = fmaf(hi, hi, s);
    }
    csq[t] = s;
  }
  __syncthreads();

  // ---- P3: each wave: its 16 channels x all 16 position-subtiles
#pragma unroll 4
  for (int s = 0; s < 16; ++s) {
    // A fragments: lane (q,r) holds patch[pos=s*16+r][k=32ks+8q .. +7]
    bf16x8 av[NKS];
#pragma unroll
    for (int ks = 0; ks < NKS; ++ks) {
      int xrow = s * 16 + r + 2 * ks + jtq;
      av[ks] = *(const bf16x8*)(lds + OFF_XT + xrow * (RSTR * 2) + half * 16);
    }
    // two accumulator chains (shorter MFMA latency chain), summed at the end
    f32x4 accA = {0.f, 0.f, 0.f, 0.f}, accB = {0.f, 0.f, 0.f, 0.f};
    {
      union { uint4 u; bf16x8 v; } w0, w1, w2, w3, w4;
      w0.u = wfrag[0]; w1.u = wfrag[1]; w2.u = wfrag[2];
      w3.u = wfrag[3]; w4.u = wfrag[4];
      accA = __builtin_amdgcn_mfma_f32_16x16x32_bf16(av[0], w0.v, accA, 0, 0, 0);
      accB = __builtin_amdgcn_mfma_f32_16x16x32_bf16(av[1], w1.v, accB, 0, 0, 0);
      accA = __builtin_amdgcn_mfma_f32_16x16x32_bf16(av[2], w2.v, accA, 0, 0, 0);
      accB = __builtin_amdgcn_mfma_f32_16x16x32_bf16(av[3], w3.v, accB, 0, 0, 0);
      accA = __builtin_amdgcn_mfma_f32_16x16x32_bf16(av[4], w4.v, accA, 0, 0, 0);
    }
    const f32x4 acc = accA + accB;

    // time channel: 3 broadcast float4 reads of csq + running 9-window sums
    const int base = s * 16 + q * 4;
    const f32x4* c4 = (const f32x4*)(csq + base);
    f32x4 ca = c4[0], cm = c4[1], cc = c4[2];
    float v[12] = {ca[0], ca[1], ca[2], ca[3], cm[0], cm[1], cm[2], cm[3],
                   cc[0], cc[1], cc[2], cc[3]};
    float ws0 = ((v[0] + v[1]) + (v[2] + v[3])) + ((v[4] + v[5]) + (v[6] + v[7])) + v[8];
    float ws1 = ws0 - v[0] + v[9];
    float ws2 = ws1 - v[1] + v[10];
    float ws3 = ws2 - v[2] + v[11];
    const float wsv[4] = {ws0, ws1, ws2, ws3};

    float h[4], psum[4];
#pragma unroll
    for (int g = 0; g < 4; ++g) {
      float tmg = sqrtf(1.f + wsv[g]);
      float hh = fmaf(w0v, tmg, acc[g]) + bv;
      hh = fmaxf(hh, 0.f);
      h[g] = hh;
      psum[g] = hh * hh;
    }
    if (row < NW) {
      *(float4*)(out + ((size_t)b * OUTC + row + 1) * L_ + p0 + s * 16 + q * 4) =
          make_float4(h[0], h[1], h[2], h[3]);
    }
    // reduce h^2 over the wave's 16 channels (xor over r bits only)
#pragma unroll
    for (int m = 1; m <= 8; m <<= 1) {
#pragma unroll
      for (int g = 0; g < 4; ++g) psum[g] += __shfl_xor(psum[g], m, 64);
    }
    if (r == 0) {
      *(f32x4*)(red + wv * PP + s * 16 + q * 4) =
          (f32x4){psum[0], psum[1], psum[2], psum[3]};
    }
  }
  __syncthreads();

  // ---- P4: cross-wave combine -> t_out (channel 0), coalesced float4 store
  if (wv == 0) {
    const f32x4* r4 = (const f32x4*)red;
    f32x4 s0 = r4[lane], s1 = r4[64 + lane], s2 = r4[128 + lane], s3 = r4[192 + lane];
    float4 t;
    t.x = sqrtf(1.f + s0[0] + s1[0] + s2[0] + s3[0]);
    t.y = sqrtf(1.f + s0[1] + s1[1] + s2[1] + s3[1]);
    t.z = sqrtf(1.f + s0[2] + s1[2] + s2[2] + s3[2]);
    t.w = sqrtf(1.f + s0[3] + s1[3] + s2[3] + s3[3]);
    *(float4*)(out + (size_t)b * OUTC * L_ + p0 + 4 * lane) = t;
  }
}

extern "C" void kernel_launch(void* const* d_in, const int* in_sizes, int n_in,
                              void* d_out, int out_size, void* d_ws, size_t ws_size,
                              hipStream_t stream) {
  const float* x = (const float*)d_in[0];
  const float* W = (const float*)d_in[1];
  const float* bias = (const float*)d_in[2];
  float* out = (float*)d_out;
  u16t* wbf = (u16t*)d_ws;  // 64*160*2 = 20480 B

  hipLaunchKernelGGL(prep_w, dim3((OUTC * KT + 255) / 256), dim3(256), 0, stream, W, wbf);
  hipLaunchKernelGGL(lorentz_mfma, dim3(L_ / PP, B_), dim3(256), 0, stream,
                     x, W, bias, wbf, out);
}